// Round 9
// baseline (133.868 us; speedup 1.0000x reference)
//
#include <hip/hip_runtime.h>

#define NN 768
#define FD 256
#define HD 128

__device__ __forceinline__ float relu(float x) { return x > 0.f ? x : 0.f; }
__device__ __forceinline__ void fma4(float4& a, float s, float4 v) {
    a.x = fmaf(s, v.x, a.x); a.y = fmaf(s, v.y, a.y);
    a.z = fmaf(s, v.z, a.z); a.w = fmaf(s, v.w, a.w);
}
__device__ __forceinline__ float rdot(float4 a, float4 b, float4 w) {
    float s = relu(a.x + b.x) * w.x;
    s = fmaf(relu(a.y + b.y), w.y, s);
    s = fmaf(relu(a.z + b.z), w.z, s);
    s = fmaf(relu(a.w + b.w), w.w, s);
    return s;
}

// K1: blocks 0..255 (768 thr): rows 3b..3b+2 -> dinv[i], t1D=dinv*(x@w1)
//     block 256: c[k] = temb[t]@we1[2H:] + be1
__global__ __launch_bounds__(768) void k_prep(
        const float* __restrict__ x, const float* __restrict__ adj,
        const float* __restrict__ w1, const float* __restrict__ temb,
        const float* __restrict__ we1, const float* __restrict__ be1,
        const int* __restrict__ tptr, float* __restrict__ dinv,
        float* __restrict__ cvec, float* __restrict__ t1D) {
    int b = blockIdx.x, tid = threadIdx.x;
    if (b == 256) {
        __shared__ float ts[HD];
        if (tid < HD) ts[tid] = temb[tptr[0] * HD + tid];
        __syncthreads();
        if (tid < HD) {
            float a0 = be1[tid], a1 = 0.f, a2 = 0.f, a3 = 0.f;
            for (int m = 0; m < HD; m += 4) {
                a0 = fmaf(ts[m + 0], we1[(2 * HD + m + 0) * HD + tid], a0);
                a1 = fmaf(ts[m + 1], we1[(2 * HD + m + 1) * HD + tid], a1);
                a2 = fmaf(ts[m + 2], we1[(2 * HD + m + 2) * HD + tid], a2);
                a3 = fmaf(ts[m + 3], we1[(2 * HD + m + 3) * HD + tid], a3);
            }
            cvec[tid] = (a0 + a1) + (a2 + a3);
        }
        return;
    }
    int i0 = b * 3;
    __shared__ float xs[3][FD];
    __shared__ float part[3][2][HD];
    __shared__ float red[12];
    __shared__ float sdi[3];
    if (tid < 192) {
        int row = tid >> 6, m4 = tid & 63;
        *(float4*)&xs[row][m4 * 4] = *(const float4*)&x[(i0 + row) * FD + m4 * 4];
    }
    {
        int r2 = tid >> 8, s = tid & 255;
        float sum = 0.f;
        if (s < 192) {
            float4 a = *(const float4*)&adj[(i0 + r2) * NN + s * 4];
            sum = (a.x + a.y) + (a.z + a.w);
        }
#pragma unroll
        for (int off = 32; off > 0; off >>= 1) sum += __shfl_down(sum, off, 64);
        if ((tid & 63) == 0) red[tid >> 6] = sum;
    }
    __syncthreads();
    if (tid < 3) {
        float t = (red[4 * tid] + red[4 * tid + 1]) + (red[4 * tid + 2] + red[4 * tid + 3]);
        float d = rsqrtf(t + 1.f);
        sdi[tid] = d; dinv[i0 + tid] = d;
    }
    __syncthreads();
    int r = tid >> 8, half = (tid >> 7) & 1, k = tid & 127;
    float a0 = 0.f, a1 = 0.f, a2 = 0.f, a3 = 0.f;
    for (int g = 128 * half; g < 128 * half + 128; g += 16) {
        float wv[16];
#pragma unroll
        for (int u = 0; u < 16; ++u) wv[u] = w1[(g + u) * HD + k];
#pragma unroll
        for (int u = 0; u < 16; ++u) {
            float xv = xs[r][g + u];
            if ((u & 3) == 0) a0 = fmaf(xv, wv[u], a0);
            else if ((u & 3) == 1) a1 = fmaf(xv, wv[u], a1);
            else if ((u & 3) == 2) a2 = fmaf(xv, wv[u], a2);
            else a3 = fmaf(xv, wv[u], a3);
        }
    }
    part[r][half][k] = (a0 + a1) + (a2 + a3);
    __syncthreads();
    if (half == 0) t1D[(i0 + r) * HD + k] = sdi[r] * (part[r][0][k] + part[r][1][k]);
}

// Split-k GEMM: 384 blocks = 48 i-tiles(16 rows) x 8 segs(96 j), 128 thr.
// Thread: 4 rows x 4 cols. Inner loop: 4-j groups, all-b128 LDS reads.
__global__ __launch_bounds__(128) void k_agg(const float* __restrict__ adj,
                                             const float* __restrict__ tin,
                                             float* __restrict__ P) {
    int it = blockIdx.x % 48, seg = blockIdx.x / 48;
    int i0 = it * 16, j0 = seg * 96;
    __shared__ float adjS[16][100];
    __shared__ float TS[96][132];
    int tid = threadIdx.x;
#pragma unroll
    for (int f = tid; f < 384; f += 128) {
        int r = f / 24, c4 = f % 24;
        *(float4*)&adjS[r][c4 * 4] = *(const float4*)&adj[(i0 + r) * NN + j0 + c4 * 4];
    }
#pragma unroll
    for (int f = tid; f < 3072; f += 128) {
        int r = f >> 5, c4 = f & 31;
        *(float4*)&TS[r][c4 * 4] = *(const float4*)&tin[(j0 + r) * HD + c4 * 4];
    }
    __syncthreads();
    int tk = tid & 31, tr = tid >> 5;  // rows tr*4.., cols tk*4..
    float4 acc0 = {0,0,0,0}, acc1 = {0,0,0,0}, acc2 = {0,0,0,0}, acc3 = {0,0,0,0};
#pragma unroll 4
    for (int jg = 0; jg < 24; ++jg) {
        int j = jg * 4;
        float4 a0 = *(float4*)&adjS[tr * 4 + 0][j];
        float4 a1 = *(float4*)&adjS[tr * 4 + 1][j];
        float4 a2 = *(float4*)&adjS[tr * 4 + 2][j];
        float4 a3 = *(float4*)&adjS[tr * 4 + 3][j];
        float4 t0 = *(float4*)&TS[j + 0][tk * 4];
        float4 t1 = *(float4*)&TS[j + 1][tk * 4];
        float4 t2 = *(float4*)&TS[j + 2][tk * 4];
        float4 t3 = *(float4*)&TS[j + 3][tk * 4];
        fma4(acc0, a0.x, t0); fma4(acc0, a0.y, t1); fma4(acc0, a0.z, t2); fma4(acc0, a0.w, t3);
        fma4(acc1, a1.x, t0); fma4(acc1, a1.y, t1); fma4(acc1, a1.z, t2); fma4(acc1, a1.w, t3);
        fma4(acc2, a2.x, t0); fma4(acc2, a2.y, t1); fma4(acc2, a2.z, t2); fma4(acc2, a2.w, t3);
        fma4(acc3, a3.x, t0); fma4(acc3, a3.y, t1); fma4(acc3, a3.z, t2); fma4(acc3, a3.w, t3);
    }
    float* base = P + (size_t)seg * (NN * HD) + (i0 + tr * 4) * HD + tk * 4;
    *(float4*)&base[0 * HD] = acc0;
    *(float4*)&base[1 * HD] = acc1;
    *(float4*)&base[2 * HD] = acc2;
    *(float4*)&base[3 * HD] = acc3;
}

// Reduce 8 partials + self + relu -> g; then outD = dinv * (g @ w2). 256 blocks x 384 thr.
__global__ __launch_bounds__(384) void k_fin_w(
        const float* __restrict__ P, const float* __restrict__ tin,
        const float* __restrict__ dinv, const float* __restrict__ w2,
        float* __restrict__ outD) {
    __shared__ float gs[3][HD];
    __shared__ float part[3][4][HD];
    int tid = threadIdx.x, i0 = blockIdx.x * 3;
    {
        int r = tid >> 7, k = tid & 127;
        int i = i0 + r;
        float s = tin[i * HD + k];
#pragma unroll
        for (int seg = 0; seg < 8; ++seg) s += P[(size_t)seg * (NN * HD) + i * HD + k];
        gs[r][k] = relu(dinv[i] * s);
    }
    __syncthreads();
    int r = tid >> 7, ms = (tid >> 5) & 3, kq = tid & 31;
    const float4* w24 = (const float4*)w2;
    float4 acc = {0,0,0,0};
#pragma unroll
    for (int u = 0; u < 32; ++u) {
        int m = ms * 32 + u;
        fma4(acc, gs[r][m], w24[m * 32 + kq]);
    }
    *(float4*)&part[r][ms][kq * 4] = acc;
    __syncthreads();
    int k = tid & 127;
    float s = part[r][0][k] + part[r][1][k] + part[r][2][k] + part[r][3][k];
    outD[(i0 + r) * HD + k] = dinv[i0 + r] * s;
}

// Reduce 8 partials + self + relu -> h2; p = h2@we1[:H]+c, q = h2@we1[H:2H].
__global__ __launch_bounds__(384) void k_fin_pq(
        const float* __restrict__ P, const float* __restrict__ tin,
        const float* __restrict__ dinv, const float* __restrict__ we1,
        const float* __restrict__ cvec, float* __restrict__ p, float* __restrict__ q) {
    __shared__ float gs[3][HD];
    __shared__ float part[3][8][HD];
    int tid = threadIdx.x, i0 = blockIdx.x * 3;
    {
        int r = tid >> 7, k = tid & 127;
        int i = i0 + r;
        float s = tin[i * HD + k];
#pragma unroll
        for (int seg = 0; seg < 8; ++seg) s += P[(size_t)seg * (NN * HD) + i * HD + k];
        gs[r][k] = relu(dinv[i] * s);
    }
    __syncthreads();
    int r = tid >> 7, ms = (tid >> 5) & 3, kq = tid & 31;
    const float4* we14 = (const float4*)we1;
    float4 ap = {0,0,0,0}, aq = {0,0,0,0};
#pragma unroll
    for (int u = 0; u < 32; ++u) {
        int m = ms * 32 + u;
        float g = gs[r][m];
        fma4(ap, g, we14[m * 32 + kq]);
        fma4(aq, g, we14[(HD + m) * 32 + kq]);
    }
    *(float4*)&part[r][ms][kq * 4] = ap;
    *(float4*)&part[r][ms + 4][kq * 4] = aq;
    __syncthreads();
    int k = tid & 127;
    float sp = part[r][0][k] + part[r][1][k] + part[r][2][k] + part[r][3][k];
    float sq = part[r][4][k] + part[r][5][k] + part[r][6][k] + part[r][7][k];
    p[(i0 + r) * HD + k] = cvec[k] + sp;
    q[(i0 + r) * HD + k] = sq;
}

// K4: 32x32 tile pairs (bi<=bj), 300 blocks, 256 thr, 2x2 per thread, both dirs.
__global__ __launch_bounds__(256) void k_pair(
        const float* __restrict__ p, const float* __restrict__ q,
        const float* __restrict__ we2, const float* __restrict__ be2,
        float* __restrict__ out) {
    int t = blockIdx.x;
    int bj = (int)((sqrtf(8.f * t + 1.f) - 1.f) * 0.5f);
    while ((bj + 1) * (bj + 2) / 2 <= t) ++bj;
    while (bj * (bj + 1) / 2 > t) --bj;
    int bi = t - bj * (bj + 1) / 2;
    int i0 = bi * 32, j0 = bj * 32;
    __shared__ float spi[32][68], sqi[32][68], spj[32][68], sqj[32][68];
    __shared__ float w2s[HD];
    int tid = threadIdx.x;
    int tx = tid & 15, ty = tid >> 4;
    if (tid < HD) w2s[tid] = we2[tid];
    float accij[2][2] = {{0.f, 0.f}, {0.f, 0.f}};
    float accji[2][2] = {{0.f, 0.f}, {0.f, 0.f}};
    for (int h = 0; h < 2; ++h) {
        __syncthreads();
        int kb = h * 64;
        for (int idx = tid; idx < 512; idx += 256) {
            int r = idx >> 4, c4 = idx & 15;
            *(float4*)&spi[r][c4 * 4] = *(const float4*)&p[(i0 + r) * HD + kb + c4 * 4];
            *(float4*)&sqi[r][c4 * 4] = *(const float4*)&q[(i0 + r) * HD + kb + c4 * 4];
            *(float4*)&spj[r][c4 * 4] = *(const float4*)&p[(j0 + r) * HD + kb + c4 * 4];
            *(float4*)&sqj[r][c4 * 4] = *(const float4*)&q[(j0 + r) * HD + kb + c4 * 4];
        }
        __syncthreads();
#pragma unroll 8
        for (int k4 = 0; k4 < 16; ++k4) {
            float4 w = *(float4*)&w2s[kb + k4 * 4];
            float4 Pi0 = *(float4*)&spi[2 * ty + 0][k4 * 4];
            float4 Pi1 = *(float4*)&spi[2 * ty + 1][k4 * 4];
            float4 Qi0 = *(float4*)&sqi[2 * ty + 0][k4 * 4];
            float4 Qi1 = *(float4*)&sqi[2 * ty + 1][k4 * 4];
            float4 Pj0 = *(float4*)&spj[2 * tx + 0][k4 * 4];
            float4 Pj1 = *(float4*)&spj[2 * tx + 1][k4 * 4];
            float4 Qj0 = *(float4*)&sqj[2 * tx + 0][k4 * 4];
            float4 Qj1 = *(float4*)&sqj[2 * tx + 1][k4 * 4];
            accij[0][0] += rdot(Pi0, Qj0, w); accji[0][0] += rdot(Pj0, Qi0, w);
            accij[0][1] += rdot(Pi0, Qj1, w); accji[0][1] += rdot(Pj1, Qi0, w);
            accij[1][0] += rdot(Pi1, Qj0, w); accji[1][0] += rdot(Pj0, Qi1, w);
            accij[1][1] += rdot(Pi1, Qj1, w); accji[1][1] += rdot(Pj1, Qi1, w);
        }
    }
    float bias = be2[0];
#pragma unroll
    for (int e = 0; e < 2; ++e)
#pragma unroll
        for (int f = 0; f < 2; ++f) {
            int i = i0 + 2 * ty + e, j = j0 + 2 * tx + f;
            float lij = accij[e][f] + bias, lji = accji[e][f] + bias;
            float v = 0.5f * (1.f / (1.f + __expf(-lij)) + 1.f / (1.f + __expf(-lji)));
            out[i * NN + j] = v;
            out[j * NN + i] = v;
        }
}

extern "C" void kernel_launch(void* const* d_in, const int* in_sizes, int n_in,
                              void* d_out, int out_size, void* d_ws, size_t ws_size,
                              hipStream_t stream) {
    const float* x    = (const float*)d_in[0];
    const float* adj  = (const float*)d_in[1];
    const float* w1   = (const float*)d_in[2];
    const float* w2   = (const float*)d_in[3];
    const float* temb = (const float*)d_in[4];
    const float* we1  = (const float*)d_in[5];
    const float* be1  = (const float*)d_in[6];
    const float* we2  = (const float*)d_in[7];
    const float* be2  = (const float*)d_in[8];
    const int* tptr   = (const int*)d_in[9];
    float* out        = (float*)d_out;

    float* ws   = (float*)d_ws;
    float* dinv = ws;               // 768
    float* c    = ws + 768;         // 128
    float* A    = ws + 1024;        // t1D, later p
    float* B    = A + NN * HD;      // t2D
    float* C    = B + NN * HD;      // q
    float* P    = C + NN * HD;      // 8 x 768 x 128 split-k partials (3.1 MB)

    k_prep  <<<257, 768, 0, stream>>>(x, adj, w1, temb, we1, be1, tptr, dinv, c, A);
    k_agg   <<<384, 128, 0, stream>>>(adj, A, P);
    k_fin_w <<<256, 384, 0, stream>>>(P, A, dinv, w2, B);
    k_agg   <<<384, 128, 0, stream>>>(adj, B, P);
    k_fin_pq<<<256, 384, 0, stream>>>(P, B, dinv, we1, c, A, C);
    k_pair  <<<300, 256, 0, stream>>>(A, C, we2, be2, out);
}

// Round 10
// 127.772 us; speedup vs baseline: 1.0477x; 1.0477x over previous
//
#include <hip/hip_runtime.h>

#define NN 768
#define FD 256
#define HD 128

__device__ __forceinline__ float relu(float x) { return x > 0.f ? x : 0.f; }
__device__ __forceinline__ void fma4(float4& a, float s, float4 v) {
    a.x = fmaf(s, v.x, a.x); a.y = fmaf(s, v.y, a.y);
    a.z = fmaf(s, v.z, a.z); a.w = fmaf(s, v.w, a.w);
}
__device__ __forceinline__ float rdot(float4 a, float4 b, float4 w) {
    float s = relu(a.x + b.x) * w.x;
    s = fmaf(relu(a.y + b.y), w.y, s);
    s = fmaf(relu(a.z + b.z), w.z, s);
    s = fmaf(relu(a.w + b.w), w.w, s);
    return s;
}

// K1: blocks 0..255 (768 thr): rows 3b..3b+2 -> dinv[i], t1D=dinv*(x@w1)
//     block 256: c[k] = temb[t]@we1[2H:] + be1
__global__ __launch_bounds__(768) void k_prep(
        const float* __restrict__ x, const float* __restrict__ adj,
        const float* __restrict__ w1, const float* __restrict__ temb,
        const float* __restrict__ we1, const float* __restrict__ be1,
        const int* __restrict__ tptr, float* __restrict__ dinv,
        float* __restrict__ cvec, float* __restrict__ t1D) {
    int b = blockIdx.x, tid = threadIdx.x;
    if (b == 256) {
        __shared__ float ts[HD];
        if (tid < HD) ts[tid] = temb[tptr[0] * HD + tid];
        __syncthreads();
        if (tid < HD) {
            float a0 = be1[tid], a1 = 0.f, a2 = 0.f, a3 = 0.f;
            for (int m = 0; m < HD; m += 4) {
                a0 = fmaf(ts[m + 0], we1[(2 * HD + m + 0) * HD + tid], a0);
                a1 = fmaf(ts[m + 1], we1[(2 * HD + m + 1) * HD + tid], a1);
                a2 = fmaf(ts[m + 2], we1[(2 * HD + m + 2) * HD + tid], a2);
                a3 = fmaf(ts[m + 3], we1[(2 * HD + m + 3) * HD + tid], a3);
            }
            cvec[tid] = (a0 + a1) + (a2 + a3);
        }
        return;
    }
    int i0 = b * 3;
    __shared__ float xs[3][FD];
    __shared__ float part[3][2][HD];
    __shared__ float red[12];
    __shared__ float sdi[3];
    if (tid < 192) {
        int row = tid >> 6, m4 = tid & 63;
        *(float4*)&xs[row][m4 * 4] = *(const float4*)&x[(i0 + row) * FD + m4 * 4];
    }
    {
        int r2 = tid >> 8, s = tid & 255;
        float sum = 0.f;
        if (s < 192) {
            float4 a = *(const float4*)&adj[(i0 + r2) * NN + s * 4];
            sum = (a.x + a.y) + (a.z + a.w);
        }
#pragma unroll
        for (int off = 32; off > 0; off >>= 1) sum += __shfl_down(sum, off, 64);
        if ((tid & 63) == 0) red[tid >> 6] = sum;
    }
    __syncthreads();
    if (tid < 3) {
        float t = (red[4 * tid] + red[4 * tid + 1]) + (red[4 * tid + 2] + red[4 * tid + 3]);
        float d = rsqrtf(t + 1.f);
        sdi[tid] = d; dinv[i0 + tid] = d;
    }
    __syncthreads();
    int r = tid >> 8, half = (tid >> 7) & 1, k = tid & 127;
    float a0 = 0.f, a1 = 0.f, a2 = 0.f, a3 = 0.f;
    for (int g = 128 * half; g < 128 * half + 128; g += 16) {
        float wv[16];
#pragma unroll
        for (int u = 0; u < 16; ++u) wv[u] = w1[(g + u) * HD + k];
#pragma unroll
        for (int u = 0; u < 16; ++u) {
            float xv = xs[r][g + u];
            if ((u & 3) == 0) a0 = fmaf(xv, wv[u], a0);
            else if ((u & 3) == 1) a1 = fmaf(xv, wv[u], a1);
            else if ((u & 3) == 2) a2 = fmaf(xv, wv[u], a2);
            else a3 = fmaf(xv, wv[u], a3);
        }
    }
    part[r][half][k] = (a0 + a1) + (a2 + a3);
    __syncthreads();
    if (half == 0) t1D[(i0 + r) * HD + k] = sdi[r] * (part[r][0][k] + part[r][1][k]);
}

// Split-k GEMM: P[seg][i][k] partial of sum_j adj[i,j]*tin[j,k] over j-seg of 48.
// 384 blocks = 24 i-tiles(32 rows) x 16 j-segs. 256 thr: 4 rows x 4 cols/thread.
// adj tile stored TRANSPOSED in LDS so each thread reads its 4 rows as one b128.
__global__ __launch_bounds__(256) void k_agg(const float* __restrict__ adj,
                                             const float* __restrict__ tin,
                                             float* __restrict__ P) {
    int it = blockIdx.x % 24, seg = blockIdx.x / 24;
    int i0 = it * 32, j0 = seg * 48;
    __shared__ float adjT[48][36];   // [j][r], rows 16B-aligned (36*4=144B)
    __shared__ float TS[48][132];
    int tid = threadIdx.x;
    for (int f = tid; f < 384; f += 256) {
        int r = f / 12, c4 = f % 12;
        float4 a = *(const float4*)&adj[(i0 + r) * NN + j0 + c4 * 4];
        adjT[c4 * 4 + 0][r] = a.x;
        adjT[c4 * 4 + 1][r] = a.y;
        adjT[c4 * 4 + 2][r] = a.z;
        adjT[c4 * 4 + 3][r] = a.w;
    }
    for (int f = tid; f < 1536; f += 256) {
        int r = f >> 5, c4 = f & 31;
        *(float4*)&TS[r][c4 * 4] = *(const float4*)&tin[(j0 + r) * HD + c4 * 4];
    }
    __syncthreads();
    int tk = tid & 31, tr = tid >> 5;  // rows tr*4..tr*4+3, cols tk*4..tk*4+3
    float4 acc0 = {0,0,0,0}, acc1 = {0,0,0,0}, acc2 = {0,0,0,0}, acc3 = {0,0,0,0};
#pragma unroll 6
    for (int jg = 0; jg < 12; ++jg) {
        int j = jg * 4;
        float4 ar0 = *(float4*)&adjT[j + 0][tr * 4];
        float4 ar1 = *(float4*)&adjT[j + 1][tr * 4];
        float4 ar2 = *(float4*)&adjT[j + 2][tr * 4];
        float4 ar3 = *(float4*)&adjT[j + 3][tr * 4];
        float4 t0 = *(float4*)&TS[j + 0][tk * 4];
        float4 t1 = *(float4*)&TS[j + 1][tk * 4];
        float4 t2 = *(float4*)&TS[j + 2][tk * 4];
        float4 t3 = *(float4*)&TS[j + 3][tk * 4];
        fma4(acc0, ar0.x, t0); fma4(acc0, ar1.x, t1); fma4(acc0, ar2.x, t2); fma4(acc0, ar3.x, t3);
        fma4(acc1, ar0.y, t0); fma4(acc1, ar1.y, t1); fma4(acc1, ar2.y, t2); fma4(acc1, ar3.y, t3);
        fma4(acc2, ar0.z, t0); fma4(acc2, ar1.z, t1); fma4(acc2, ar2.z, t2); fma4(acc2, ar3.z, t3);
        fma4(acc3, ar0.w, t0); fma4(acc3, ar1.w, t1); fma4(acc3, ar2.w, t2); fma4(acc3, ar3.w, t3);
    }
    float* base = P + (size_t)seg * (NN * HD) + (i0 + tr * 4) * HD + tk * 4;
    *(float4*)&base[0 * HD] = acc0;
    *(float4*)&base[1 * HD] = acc1;
    *(float4*)&base[2 * HD] = acc2;
    *(float4*)&base[3 * HD] = acc3;
}

// Reduce 16 partials + self + relu -> g; then outD = dinv * (g @ w2). 256 blocks x 384 thr.
__global__ __launch_bounds__(384) void k_fin_w(
        const float* __restrict__ P, const float* __restrict__ tin,
        const float* __restrict__ dinv, const float* __restrict__ w2,
        float* __restrict__ outD) {
    __shared__ float gs[3][HD];
    __shared__ float part[3][4][HD];
    int tid = threadIdx.x, i0 = blockIdx.x * 3;
    {
        int r = tid >> 7, k = tid & 127;
        int i = i0 + r;
        float s = tin[i * HD + k];
#pragma unroll
        for (int seg = 0; seg < 16; ++seg) s += P[(size_t)seg * (NN * HD) + i * HD + k];
        gs[r][k] = relu(dinv[i] * s);
    }
    __syncthreads();
    int r = tid >> 7, ms = (tid >> 5) & 3, kq = tid & 31;
    const float4* w24 = (const float4*)w2;
    float4 acc = {0,0,0,0};
#pragma unroll
    for (int u = 0; u < 32; ++u) {
        int m = ms * 32 + u;
        fma4(acc, gs[r][m], w24[m * 32 + kq]);
    }
    *(float4*)&part[r][ms][kq * 4] = acc;
    __syncthreads();
    int k = tid & 127;
    float s = part[r][0][k] + part[r][1][k] + part[r][2][k] + part[r][3][k];
    outD[(i0 + r) * HD + k] = dinv[i0 + r] * s;
}

// Reduce 16 partials + self + relu -> h2; p = h2@we1[:H]+c, q = h2@we1[H:2H].
__global__ __launch_bounds__(384) void k_fin_pq(
        const float* __restrict__ P, const float* __restrict__ tin,
        const float* __restrict__ dinv, const float* __restrict__ we1,
        const float* __restrict__ cvec, float* __restrict__ p, float* __restrict__ q) {
    __shared__ float gs[3][HD];
    __shared__ float part[3][8][HD];
    int tid = threadIdx.x, i0 = blockIdx.x * 3;
    {
        int r = tid >> 7, k = tid & 127;
        int i = i0 + r;
        float s = tin[i * HD + k];
#pragma unroll
        for (int seg = 0; seg < 16; ++seg) s += P[(size_t)seg * (NN * HD) + i * HD + k];
        gs[r][k] = relu(dinv[i] * s);
    }
    __syncthreads();
    int r = tid >> 7, ms = (tid >> 5) & 3, kq = tid & 31;
    const float4* we14 = (const float4*)we1;
    float4 ap = {0,0,0,0}, aq = {0,0,0,0};
#pragma unroll
    for (int u = 0; u < 32; ++u) {
        int m = ms * 32 + u;
        float g = gs[r][m];
        fma4(ap, g, we14[m * 32 + kq]);
        fma4(aq, g, we14[(HD + m) * 32 + kq]);
    }
    *(float4*)&part[r][ms][kq * 4] = ap;
    *(float4*)&part[r][ms + 4][kq * 4] = aq;
    __syncthreads();
    int k = tid & 127;
    float sp = part[r][0][k] + part[r][1][k] + part[r][2][k] + part[r][3][k];
    float sq = part[r][4][k] + part[r][5][k] + part[r][6][k] + part[r][7][k];
    p[(i0 + r) * HD + k] = cvec[k] + sp;
    q[(i0 + r) * HD + k] = sq;
}

// K4: 32x32 tile pairs (bi<=bj), 300 blocks, 256 thr, 2x2 per thread, both dirs.
__global__ __launch_bounds__(256) void k_pair(
        const float* __restrict__ p, const float* __restrict__ q,
        const float* __restrict__ we2, const float* __restrict__ be2,
        float* __restrict__ out) {
    int t = blockIdx.x;
    int bj = (int)((sqrtf(8.f * t + 1.f) - 1.f) * 0.5f);
    while ((bj + 1) * (bj + 2) / 2 <= t) ++bj;
    while (bj * (bj + 1) / 2 > t) --bj;
    int bi = t - bj * (bj + 1) / 2;
    int i0 = bi * 32, j0 = bj * 32;
    __shared__ float spi[32][68], sqi[32][68], spj[32][68], sqj[32][68];
    __shared__ float w2s[HD];
    int tid = threadIdx.x;
    int tx = tid & 15, ty = tid >> 4;
    if (tid < HD) w2s[tid] = we2[tid];
    float accij[2][2] = {{0.f, 0.f}, {0.f, 0.f}};
    float accji[2][2] = {{0.f, 0.f}, {0.f, 0.f}};
    for (int h = 0; h < 2; ++h) {
        __syncthreads();
        int kb = h * 64;
        for (int idx = tid; idx < 512; idx += 256) {
            int r = idx >> 4, c4 = idx & 15;
            *(float4*)&spi[r][c4 * 4] = *(const float4*)&p[(i0 + r) * HD + kb + c4 * 4];
            *(float4*)&sqi[r][c4 * 4] = *(const float4*)&q[(i0 + r) * HD + kb + c4 * 4];
            *(float4*)&spj[r][c4 * 4] = *(const float4*)&p[(j0 + r) * HD + kb + c4 * 4];
            *(float4*)&sqj[r][c4 * 4] = *(const float4*)&q[(j0 + r) * HD + kb + c4 * 4];
        }
        __syncthreads();
#pragma unroll 8
        for (int k4 = 0; k4 < 16; ++k4) {
            float4 w = *(float4*)&w2s[kb + k4 * 4];
            float4 Pi0 = *(float4*)&spi[2 * ty + 0][k4 * 4];
            float4 Pi1 = *(float4*)&spi[2 * ty + 1][k4 * 4];
            float4 Qi0 = *(float4*)&sqi[2 * ty + 0][k4 * 4];
            float4 Qi1 = *(float4*)&sqi[2 * ty + 1][k4 * 4];
            float4 Pj0 = *(float4*)&spj[2 * tx + 0][k4 * 4];
            float4 Pj1 = *(float4*)&spj[2 * tx + 1][k4 * 4];
            float4 Qj0 = *(float4*)&sqj[2 * tx + 0][k4 * 4];
            float4 Qj1 = *(float4*)&sqj[2 * tx + 1][k4 * 4];
            accij[0][0] += rdot(Pi0, Qj0, w); accji[0][0] += rdot(Pj0, Qi0, w);
            accij[0][1] += rdot(Pi0, Qj1, w); accji[0][1] += rdot(Pj1, Qi0, w);
            accij[1][0] += rdot(Pi1, Qj0, w); accji[1][0] += rdot(Pj0, Qi1, w);
            accij[1][1] += rdot(Pi1, Qj1, w); accji[1][1] += rdot(Pj1, Qi1, w);
        }
    }
    float bias = be2[0];
#pragma unroll
    for (int e = 0; e < 2; ++e)
#pragma unroll
        for (int f = 0; f < 2; ++f) {
            int i = i0 + 2 * ty + e, j = j0 + 2 * tx + f;
            float lij = accij[e][f] + bias, lji = accji[e][f] + bias;
            float v = 0.5f * (1.f / (1.f + __expf(-lij)) + 1.f / (1.f + __expf(-lji)));
            out[i * NN + j] = v;
            out[j * NN + i] = v;
        }
}

extern "C" void kernel_launch(void* const* d_in, const int* in_sizes, int n_in,
                              void* d_out, int out_size, void* d_ws, size_t ws_size,
                              hipStream_t stream) {
    const float* x    = (const float*)d_in[0];
    const float* adj  = (const float*)d_in[1];
    const float* w1   = (const float*)d_in[2];
    const float* w2   = (const float*)d_in[3];
    const float* temb = (const float*)d_in[4];
    const float* we1  = (const float*)d_in[5];
    const float* be1  = (const float*)d_in[6];
    const float* we2  = (const float*)d_in[7];
    const float* be2  = (const float*)d_in[8];
    const int* tptr   = (const int*)d_in[9];
    float* out        = (float*)d_out;

    float* ws   = (float*)d_ws;
    float* dinv = ws;               // 768
    float* c    = ws + 768;         // 128
    float* A    = ws + 1024;        // t1D, later p
    float* B    = A + NN * HD;      // t2D
    float* C    = B + NN * HD;      // q
    float* P    = C + NN * HD;      // 16 x 768 x 128 split-k partials (6.3 MB)

    k_prep  <<<257, 768, 0, stream>>>(x, adj, w1, temb, we1, be1, tptr, dinv, c, A);
    k_agg   <<<384, 256, 0, stream>>>(adj, A, P);
    k_fin_w <<<256, 384, 0, stream>>>(P, A, dinv, w2, B);
    k_agg   <<<384, 256, 0, stream>>>(adj, B, P);
    k_fin_pq<<<256, 384, 0, stream>>>(P, B, dinv, we1, c, A, C);
    k_pair  <<<300, 256, 0, stream>>>(A, C, we2, be2, out);
}